// Round 11
// baseline (451.018 us; speedup 1.0000x reference)
//
#include <hip/hip_runtime.h>
#include <cstddef>

#define NREL 4
#define NSUP 2         // super-relations (pairs of relations sharing a dst type)
#define HD 64
#define FD 128
#define BSHIFT 8
#define BUCKET 256     // nodes per bucket
#define CHUNK 16384    // edges per partition block

static inline int idiv_up(int a, int b) { return (a + b - 1) / b; }

typedef __attribute__((ext_vector_type(8))) short bf16x8;
typedef __attribute__((ext_vector_type(4))) float f32x4;

__device__ __forceinline__ unsigned short f2bf(float f) {
    unsigned int u = __float_as_uint(f);
    unsigned int r = (u + 0x7FFFu + ((u >> 16) & 1u)) >> 16;   // RNE
    return (unsigned short)r;
}
__device__ __forceinline__ float bflo(unsigned int v) {
    return __uint_as_float(v << 16);
}
__device__ __forceinline__ float bfhi(unsigned int v) {
    return __uint_as_float(v & 0xFFFF0000u);
}
__device__ __forceinline__ unsigned int cvtpk_bf16(float lo, float hi) {
    unsigned int r;
    asm("v_cvt_pk_bf16_f32 %0, %1, %2" : "=v"(r) : "v"(lo), "v"(hi));
    return r;
}

// ---------------- pass A: per-super-relation bucket histogram ----------------

__global__ void bhist_kernel(const int* __restrict__ dst, int* __restrict__ bhist,
                             int E2, int NBP) {
    int k = blockIdx.y;
    extern __shared__ int lh[];
    for (int i = threadIdx.x; i < NBP; i += blockDim.x) lh[i] = 0;
    __syncthreads();
    const int* dk = dst + (size_t)k * E2;
    for (int e = blockIdx.x * blockDim.x + threadIdx.x; e < E2; e += gridDim.x * blockDim.x)
        atomicAdd(&lh[dk[e] >> BSHIFT], 1);
    __syncthreads();
    int* bh = bhist + (size_t)k * NBP;
    for (int i = threadIdx.x; i < NBP; i += blockDim.x)
        if (lh[i]) atomicAdd(&bh[i], lh[i]);
}

// ---------------- pass B: exclusive scan of bucket counts (NBP <= 1024) ----------------

__global__ void bscan_kernel(const int* __restrict__ bhist, int* __restrict__ bptr,
                             int* __restrict__ gcur, int NBP, int E2) {
    int k = blockIdx.x;
    __shared__ int wsum[16];
    int tid = threadIdx.x, wid = tid >> 6, lane = tid & 63;
    int v = (tid < NBP) ? bhist[(size_t)k * NBP + tid] : 0;
    int x = v;
    #pragma unroll
    for (int off = 1; off < 64; off <<= 1) {
        int y = __shfl_up(x, off, 64);
        if (lane >= off) x += y;
    }
    if (lane == 63) wsum[wid] = x;
    __syncthreads();
    if (wid == 0) {
        int s = (lane < 16) ? wsum[lane] : 0;
        #pragma unroll
        for (int off = 1; off < 16; off <<= 1) {
            int y = __shfl_up(s, off, 64);
            if (lane >= off) s += y;
        }
        if (lane < 16) wsum[lane] = s;
    }
    __syncthreads();
    int excl = x - v + (wid ? wsum[wid - 1] : 0);
    if (tid < NBP) {
        bptr[(size_t)k * (NBP + 1) + tid] = excl;
        gcur[(size_t)k * NBP + tid] = excl;
    }
    if (tid == 0) bptr[(size_t)k * (NBP + 1) + NBP] = E2;
}

// ---------------- pass C: block-aggregated bucket partition (1024 threads) ----------
// staged[pos] = { row17 | (dst_local8 << 17), bits(w) }, grouped by dst bucket.
// row = src + N * (edge belongs to 2nd relation of the pair).

__global__ void part_kernel(const int* __restrict__ src, const int* __restrict__ dst,
                            const float* __restrict__ ew, int* __restrict__ gcur,
                            int2* __restrict__ staged, int E, int E2, int N, int NBP) {
    int k = blockIdx.y;
    extern __shared__ int sh[];
    int* lcnt = sh;          // NBP
    int* lbase = sh + NBP;   // NBP
    for (int i = threadIdx.x; i < NBP; i += blockDim.x) lcnt[i] = 0;
    __syncthreads();
    const int* sk = src + (size_t)k * E2;
    const int* dk = dst + (size_t)k * E2;
    const float* wk = ew + (size_t)k * E2;
    int base = blockIdx.x * CHUNK;
    int n = min(CHUNK, E2 - base);
    for (int i = threadIdx.x; i < n; i += blockDim.x)
        atomicAdd(&lcnt[dk[base + i] >> BSHIFT], 1);
    __syncthreads();
    for (int i = threadIdx.x; i < NBP; i += blockDim.x) {
        int c = lcnt[i];
        lbase[i] = c ? atomicAdd(&gcur[(size_t)k * NBP + i], c) : 0;
    }
    __syncthreads();
    for (int i = threadIdx.x; i < NBP; i += blockDim.x) lcnt[i] = 0;
    __syncthreads();
    int2* out = staged + (size_t)k * E2;
    for (int i = threadIdx.x; i < n; i += blockDim.x) {
        int gi = base + i;
        int d = dk[gi];
        int b = d >> BSHIFT;
        int row = sk[gi] + ((gi >= E) ? N : 0);
        int local = atomicAdd(&lcnt[b], 1);
        out[lbase[b] + local] =
            make_int2(row | ((d & (BUCKET - 1)) << 17), __float_as_int(wk[gi]));
    }
}

// ---------------- pass D: per-bucket LDS counting sort (1024 threads) ----------------
// -> node-sorted 4B edge recs + rowptr

__global__ void bsort_kernel(const int2* __restrict__ staged, const int* __restrict__ bptr,
                             int* __restrict__ rowptr, unsigned int* __restrict__ edges,
                             int E2, int N, int NBP) {
    int k = blockIdx.y;
    int b = blockIdx.x;
    __shared__ int hist[BUCKET];
    __shared__ int excl[BUCKET];
    __shared__ int cur[BUCKET];
    __shared__ int wsum2[4];
    int tid = threadIdx.x;
    int wid = tid >> 6, lane = tid & 63;
    if (tid < BUCKET) hist[tid] = 0;
    __syncthreads();
    int beg = bptr[(size_t)k * (NBP + 1) + b];
    int end = bptr[(size_t)k * (NBP + 1) + b + 1];
    const int2* in = staged + (size_t)k * E2;
    for (int i = beg + tid; i < end; i += blockDim.x)
        atomicAdd(&hist[(in[i].x >> 17) & (BUCKET - 1)], 1);
    __syncthreads();
    int v = 0, x = 0;
    if (tid < BUCKET) {   // 4 full waves scan 64 each
        v = hist[tid];
        x = v;
        #pragma unroll
        for (int off = 1; off < 64; off <<= 1) {
            int y = __shfl_up(x, off, 64);
            if (lane >= off) x += y;
        }
        if (lane == 63) wsum2[wid] = x;
    }
    __syncthreads();
    if (tid == 0) {
        int s = 0;
        #pragma unroll
        for (int j = 0; j < 4; ++j) { int t = wsum2[j]; wsum2[j] = s; s += t; }
    }
    __syncthreads();
    if (tid < BUCKET) {
        int e = x - v + wsum2[wid];
        excl[tid] = e;
        cur[tid] = e;
    }
    __syncthreads();
    unsigned int* outp = edges + (size_t)k * E2;
    for (int i = beg + tid; i < end; i += blockDim.x) {
        int2 q = in[i];
        int dl = (q.x >> 17) & (BUCKET - 1);
        int pos = atomicAdd(&cur[dl], 1);
        unsigned int wb = (unsigned int)(f2bf(__int_as_float(q.y)) & 0x7FFF);
        outp[beg + pos] = ((unsigned int)q.x & 0x1FFFFu) | (wb << 17);
    }
    int node0 = b * BUCKET;
    if (tid < BUCKET && node0 + tid < N)
        rowptr[(size_t)k * (N + 1) + node0 + tid] = beg + excl[tid];
    if (b == 0 && tid == 0) rowptr[(size_t)k * (N + 1) + N] = E2;
}

// ---------------- convert: W -> bf16 fragment-swizzled ----------------
// Wf[mat][kk][n][lane][i] = W[mat][kk*32 + (lane>>4)*8 + i][n*16 + (lane&15)]

__global__ void convw_kernel(const float* __restrict__ W, unsigned short* __restrict__ Wf,
                             int mats, int KK) {
    int tid = blockIdx.x * blockDim.x + threadIdx.x;
    int total = mats * KK * 4 * 64;
    if (tid >= total) return;
    int l = tid & 63;
    int n = (tid >> 6) & 3;
    int rest = tid >> 8;
    int kk = rest % KK;
    int mat = rest / KK;
    int h = l >> 4, c = l & 15;
    int K = KK * 32;
    const float* Wm = W + (size_t)mat * K * 64;
    unsigned short* o = Wf + (size_t)tid * 8;
    #pragma unroll
    for (int i = 0; i < 8; ++i)
        o[i] = f2bf(Wm[(size_t)(kk * 32 + h * 8 + i) * 64 + n * 16 + c]);
}

// ---------------- MFMA GEMM (bf16 X input): Y[rel] = X_{rel%2} @ W_rel ----------

template <int K>
__global__ void gemm_mfma_kernel(const unsigned short* __restrict__ Xb,
                                 const unsigned short* __restrict__ Wf,
                                 unsigned short* __restrict__ Ybase, int N) {
    constexpr int KK = K / 32;
    int rel = blockIdx.y;
    const unsigned short* X = Xb + (size_t)(rel & 1) * N * K;
    const bf16x8* Wv = reinterpret_cast<const bf16x8*>(Wf + (size_t)rel * KK * 4 * 64 * 8);
    unsigned short* Y = Ybase + (size_t)rel * N * HD;
    int tid = threadIdx.x;
    int w = tid >> 6, l = tid & 63;
    int lr = l & 15, lh = l >> 4;
    int row0 = blockIdx.x * 128 + w * 32;
    f32x4 acc00 = {0.f,0.f,0.f,0.f}, acc01 = {0.f,0.f,0.f,0.f};
    f32x4 acc02 = {0.f,0.f,0.f,0.f}, acc03 = {0.f,0.f,0.f,0.f};
    f32x4 acc10 = {0.f,0.f,0.f,0.f}, acc11 = {0.f,0.f,0.f,0.f};
    f32x4 acc12 = {0.f,0.f,0.f,0.f}, acc13 = {0.f,0.f,0.f,0.f};
    int r0 = min(row0 + lr, N - 1);
    int r1 = min(row0 + 16 + lr, N - 1);
    const unsigned short* xp0 = X + (size_t)r0 * K + lh * 8;
    const unsigned short* xp1 = X + (size_t)r1 * K + lh * 8;
    #pragma unroll
    for (int kk = 0; kk < KK; ++kk) {
        bf16x8 a0 = *reinterpret_cast<const bf16x8*>(xp0 + kk * 32);
        bf16x8 a1 = *reinterpret_cast<const bf16x8*>(xp1 + kk * 32);
        bf16x8 b0 = Wv[(kk * 4 + 0) * 64 + l];
        bf16x8 b1 = Wv[(kk * 4 + 1) * 64 + l];
        bf16x8 b2 = Wv[(kk * 4 + 2) * 64 + l];
        bf16x8 b3 = Wv[(kk * 4 + 3) * 64 + l];
        acc00 = __builtin_amdgcn_mfma_f32_16x16x32_bf16(a0, b0, acc00, 0, 0, 0);
        acc01 = __builtin_amdgcn_mfma_f32_16x16x32_bf16(a0, b1, acc01, 0, 0, 0);
        acc02 = __builtin_amdgcn_mfma_f32_16x16x32_bf16(a0, b2, acc02, 0, 0, 0);
        acc03 = __builtin_amdgcn_mfma_f32_16x16x32_bf16(a0, b3, acc03, 0, 0, 0);
        acc10 = __builtin_amdgcn_mfma_f32_16x16x32_bf16(a1, b0, acc10, 0, 0, 0);
        acc11 = __builtin_amdgcn_mfma_f32_16x16x32_bf16(a1, b1, acc11, 0, 0, 0);
        acc12 = __builtin_amdgcn_mfma_f32_16x16x32_bf16(a1, b2, acc12, 0, 0, 0);
        acc13 = __builtin_amdgcn_mfma_f32_16x16x32_bf16(a1, b3, acc13, 0, 0, 0);
    }
    // C/D layout: col = lane&15, row(in tile) = (lane>>4)*4 + reg  [HW-verified]
    #pragma unroll
    for (int reg = 0; reg < 4; ++reg) {
        int rowa = row0 + lh * 4 + reg;
        if (rowa < N) {
            unsigned short* yp = Y + (size_t)rowa * HD + lr;
            yp[0]  = f2bf(acc00[reg]);
            yp[16] = f2bf(acc01[reg]);
            yp[32] = f2bf(acc02[reg]);
            yp[48] = f2bf(acc03[reg]);
        }
        int rowb = row0 + 16 + lh * 4 + reg;
        if (rowb < N) {
            unsigned short* yp = Y + (size_t)rowb * HD + lr;
            yp[0]  = f2bf(acc10[reg]);
            yp[16] = f2bf(acc11[reg]);
            yp[32] = f2bf(acc12[reg]);
            yp[48] = f2bf(acc13[reg]);
        }
    }
}

// ---------------- MFMA GEMM (f32 X input, in-register v_cvt_pk_bf16_f32): layer 1 ----

__global__ void gemm_mfma_f32in_kernel(const float* __restrict__ X0,
                                       const float* __restrict__ X1,
                                       const unsigned short* __restrict__ Wf,
                                       unsigned short* __restrict__ Ybase, int N) {
    constexpr int K = FD;
    constexpr int KK = K / 32;
    int rel = blockIdx.y;
    const float* X = (rel & 1) ? X1 : X0;
    const bf16x8* Wv = reinterpret_cast<const bf16x8*>(Wf + (size_t)rel * KK * 4 * 64 * 8);
    unsigned short* Y = Ybase + (size_t)rel * N * HD;
    int tid = threadIdx.x;
    int w = tid >> 6, l = tid & 63;
    int lr = l & 15, lh = l >> 4;
    int row0 = blockIdx.x * 128 + w * 32;
    f32x4 acc00 = {0.f,0.f,0.f,0.f}, acc01 = {0.f,0.f,0.f,0.f};
    f32x4 acc02 = {0.f,0.f,0.f,0.f}, acc03 = {0.f,0.f,0.f,0.f};
    f32x4 acc10 = {0.f,0.f,0.f,0.f}, acc11 = {0.f,0.f,0.f,0.f};
    f32x4 acc12 = {0.f,0.f,0.f,0.f}, acc13 = {0.f,0.f,0.f,0.f};
    int r0 = min(row0 + lr, N - 1);
    int r1 = min(row0 + 16 + lr, N - 1);
    const float* xp0 = X + (size_t)r0 * K + lh * 8;
    const float* xp1 = X + (size_t)r1 * K + lh * 8;
    #pragma unroll
    for (int kk = 0; kk < KK; ++kk) {
        float4 xa0 = *reinterpret_cast<const float4*>(xp0 + kk * 32);
        float4 xa1 = *reinterpret_cast<const float4*>(xp0 + kk * 32 + 4);
        float4 xb0 = *reinterpret_cast<const float4*>(xp1 + kk * 32);
        float4 xb1 = *reinterpret_cast<const float4*>(xp1 + kk * 32 + 4);
        union { unsigned int u[4]; bf16x8 v; } ca, cb;
        ca.u[0] = cvtpk_bf16(xa0.x, xa0.y);
        ca.u[1] = cvtpk_bf16(xa0.z, xa0.w);
        ca.u[2] = cvtpk_bf16(xa1.x, xa1.y);
        ca.u[3] = cvtpk_bf16(xa1.z, xa1.w);
        cb.u[0] = cvtpk_bf16(xb0.x, xb0.y);
        cb.u[1] = cvtpk_bf16(xb0.z, xb0.w);
        cb.u[2] = cvtpk_bf16(xb1.x, xb1.y);
        cb.u[3] = cvtpk_bf16(xb1.z, xb1.w);
        bf16x8 a0 = ca.v;
        bf16x8 a1 = cb.v;
        bf16x8 b0 = Wv[(kk * 4 + 0) * 64 + l];
        bf16x8 b1 = Wv[(kk * 4 + 1) * 64 + l];
        bf16x8 b2 = Wv[(kk * 4 + 2) * 64 + l];
        bf16x8 b3 = Wv[(kk * 4 + 3) * 64 + l];
        acc00 = __builtin_amdgcn_mfma_f32_16x16x32_bf16(a0, b0, acc00, 0, 0, 0);
        acc01 = __builtin_amdgcn_mfma_f32_16x16x32_bf16(a0, b1, acc01, 0, 0, 0);
        acc02 = __builtin_amdgcn_mfma_f32_16x16x32_bf16(a0, b2, acc02, 0, 0, 0);
        acc03 = __builtin_amdgcn_mfma_f32_16x16x32_bf16(a0, b3, acc03, 0, 0, 0);
        acc10 = __builtin_amdgcn_mfma_f32_16x16x32_bf16(a1, b0, acc10, 0, 0, 0);
        acc11 = __builtin_amdgcn_mfma_f32_16x16x32_bf16(a1, b1, acc11, 0, 0, 0);
        acc12 = __builtin_amdgcn_mfma_f32_16x16x32_bf16(a1, b2, acc12, 0, 0, 0);
        acc13 = __builtin_amdgcn_mfma_f32_16x16x32_bf16(a1, b3, acc13, 0, 0, 0);
    }
    #pragma unroll
    for (int reg = 0; reg < 4; ++reg) {
        int rowa = row0 + lh * 4 + reg;
        if (rowa < N) {
            unsigned short* yp = Y + (size_t)rowa * HD + lr;
            yp[0]  = f2bf(acc00[reg]);
            yp[16] = f2bf(acc01[reg]);
            yp[32] = f2bf(acc02[reg]);
            yp[48] = f2bf(acc03[reg]);
        }
        int rowb = row0 + 16 + lh * 4 + reg;
        if (rowb < N) {
            unsigned short* yp = Y + (size_t)rowb * HD + lr;
            yp[0]  = f2bf(acc10[reg]);
            yp[16] = f2bf(acc11[reg]);
            yp[32] = f2bf(acc12[reg]);
            yp[48] = f2bf(acc13[reg]);
        }
    }
}

// ---------------- SpMM gather: one wave per dst node, combined relation pair ----------
// edge rec: row17 | wbf15<<17 (row < 2N indexes the contiguous y pair for this type).
// h = lane>>4 edge slot (4 edges per gather instr), c4 = (lane&15)*4 column quad
// (uint2 = 4 bf16 = 8 B/lane; 16 lanes cover a 128 B row). 32-edge predicated
// batches; 8 paired gathers + 8 meta loads in flight. XCD pinning: id%8 -> group.

__global__ void spmm_kernel(const unsigned short* __restrict__ Ybase,
                            const int* __restrict__ rowptr, const unsigned int* __restrict__ edges,
                            unsigned short* __restrict__ act, float* __restrict__ outp,
                            int N, int E2, int relu) {
    int id = blockIdx.x;
    int g = id & 7;
    int t = g >> 2;
    int pbi = (id >> 3) * 4 + (g & 3);
    int wave = threadIdx.x >> 6;
    int lane = threadIdx.x & 63;
    int d = pbi * 4 + wave;
    if (d >= N) return;
    int h = lane >> 4;          // edge slot 0..3
    int c4 = (lane & 15) * 4;   // column quad
    const unsigned short* Y = Ybase + (size_t)(2 * t) * N * HD;
    const unsigned int* ep = edges + (size_t)t * E2;
    int beg = rowptr[(size_t)t * (N + 1) + d];
    int end = rowptr[(size_t)t * (N + 1) + d + 1];
    float4 a[4];
    #pragma unroll
    for (int j = 0; j < 4; ++j) a[j] = make_float4(0.f, 0.f, 0.f, 0.f);
    if (beg < end) {
        int endm1 = end - 1;
        unsigned int m[8];
        #pragma unroll
        for (int j = 0; j < 8; ++j) {
            int idx = beg + 4 * j + h;
            m[j] = ep[idx < end ? idx : endm1];
        }
        for (int base = beg; ; ) {
            int nb = base + 32;
            bool more = nb < end;
            unsigned int n[8];
            if (more) {
                #pragma unroll
                for (int j = 0; j < 8; ++j) {
                    int idx = nb + 4 * j + h;
                    n[j] = ep[idx < end ? idx : endm1];
                }
            }
            uint2 y[8];
            #pragma unroll
            for (int j = 0; j < 8; ++j)
                y[j] = *reinterpret_cast<const uint2*>(Y + ((m[j] & 0x1FFFFu) * HD + c4));
            #pragma unroll
            for (int j = 0; j < 8; ++j) {
                float w = ((base + 4 * j + h) < end)
                              ? __uint_as_float((m[j] >> 17) << 16) : 0.f;
                a[j & 3].x += w * bflo(y[j].x);
                a[j & 3].y += w * bfhi(y[j].x);
                a[j & 3].z += w * bflo(y[j].y);
                a[j & 3].w += w * bfhi(y[j].y);
            }
            if (!more) break;
            base = nb;
            #pragma unroll
            for (int j = 0; j < 8; ++j) m[j] = n[j];
        }
    }
    float4 s;
    s.x = (a[0].x + a[1].x) + (a[2].x + a[3].x);
    s.y = (a[0].y + a[1].y) + (a[2].y + a[3].y);
    s.z = (a[0].z + a[1].z) + (a[2].z + a[3].z);
    s.w = (a[0].w + a[1].w) + (a[2].w + a[3].w);
    s.x += __shfl_xor(s.x, 16, 64);  s.x += __shfl_xor(s.x, 32, 64);
    s.y += __shfl_xor(s.y, 16, 64);  s.y += __shfl_xor(s.y, 32, 64);
    s.z += __shfl_xor(s.z, 16, 64);  s.z += __shfl_xor(s.z, 32, 64);
    s.w += __shfl_xor(s.w, 16, 64);  s.w += __shfl_xor(s.w, 32, 64);
    if (relu) {
        s.x = fmaxf(s.x, 0.f); s.y = fmaxf(s.y, 0.f);
        s.z = fmaxf(s.z, 0.f); s.w = fmaxf(s.w, 0.f);
    }
    if (lane < 16) {
        if (act) {
            ushort4 ob;
            ob.x = f2bf(s.x); ob.y = f2bf(s.y); ob.z = f2bf(s.z); ob.w = f2bf(s.w);
            *reinterpret_cast<ushort4*>(&act[((size_t)t * N + d) * HD + c4]) = ob;
        }
        if (outp) *reinterpret_cast<float4*>(&outp[((size_t)t * N + d) * 192 + c4]) = s;
    }
}

// ---------------- orchestration ----------------

extern "C" void kernel_launch(void* const* d_in, const int* in_sizes, int n_in,
                              void* d_out, int out_size, void* d_ws, size_t ws_size,
                              hipStream_t stream) {
    const float* x0 = (const float*)d_in[0];
    const float* x1 = (const float*)d_in[1];
    const int* src = (const int*)d_in[2];
    const int* dst = (const int*)d_in[3];
    const float* ew = (const float*)d_in[4];
    const float* W1 = (const float*)d_in[5];
    const float* Wl = (const float*)d_in[6];
    float* out = (float*)d_out;

    int N = in_sizes[0] / FD;
    int E = in_sizes[2] / NREL;
    int E2 = 2 * E;                 // edges per super-relation
    int NBP = idiv_up(N, BUCKET);   // 196 for N=50000 (must be <= 1024 for bscan)

    char* ws = (char*)d_ws;
    size_t off = 0;
    auto alloc = [&](size_t bytes) -> void* {
        void* p = ws + off;
        off = (off + bytes + 255) & ~(size_t)255;
        return p;
    };
    int* bhist   = (int*)alloc((size_t)NSUP * NBP * 4);
    int* bptr    = (int*)alloc((size_t)NSUP * (NBP + 1) * 4);
    int* gcur    = (int*)alloc((size_t)NSUP * NBP * 4);
    int* rowptr  = (int*)alloc((size_t)NSUP * (N + 1) * 4);
    unsigned int* edges = (unsigned int*)alloc((size_t)NSUP * E2 * 4);
    unsigned short* y    = (unsigned short*)alloc((size_t)NREL * N * HD * 2);
    unsigned short* actb = (unsigned short*)alloc((size_t)2 * N * HD * 2);
    unsigned short* W1f  = (unsigned short*)alloc((size_t)NREL * 4 * 4 * 64 * 8 * 2);
    unsigned short* Wlf  = (unsigned short*)alloc((size_t)16 * 2 * 4 * 64 * 8 * 2);
    int2* staged = (int2*)alloc((size_t)NSUP * E2 * 8);   // dead after bsort
    (void)ws_size;

    // weight converts (x0/x1 convert fused into layer-1 GEMM)
    convw_kernel<<<idiv_up(NREL * 4 * 4 * 64, 256), 256, 0, stream>>>(W1, W1f, NREL, 4);
    convw_kernel<<<idiv_up(16 * 2 * 4 * 64, 256), 256, 0, stream>>>(Wl, Wlf, 16, 2);

    // bucket partition + per-bucket counting sort (recomputed every call)
    hipMemsetAsync(bhist, 0, (size_t)NSUP * NBP * 4, stream);
    bhist_kernel<<<dim3(384, NSUP), 256, NBP * 4, stream>>>(dst, bhist, E2, NBP);
    bscan_kernel<<<NSUP, 1024, 0, stream>>>(bhist, bptr, gcur, NBP, E2);
    part_kernel<<<dim3(idiv_up(E2, CHUNK), NSUP), 1024, 2 * NBP * 4, stream>>>(
        src, dst, ew, gcur, staged, E, E2, N, NBP);
    bsort_kernel<<<dim3(NBP, NSUP), 1024, 0, stream>>>(staged, bptr, rowptr, edges, E2, N, NBP);

    dim3 ggrid(idiv_up(N, 128), NREL);
    int NB4 = idiv_up(N, 4);
    int sgx = idiv_up(NB4, 4) * 8;   // flat grid, id%8 -> (type, xcd-slot)

    // layer 1: h1 = relu(spmm(x @ W1)); store act(bf16) + out[:, :, 0:64]
    gemm_mfma_f32in_kernel<<<ggrid, 256, 0, stream>>>(x0, x1, W1f, y, N);
    spmm_kernel<<<sgx, 256, 0, stream>>>(y, rowptr, edges, actb, out + 0, N, E2, 1);

    // layers 2..5 with Wl[0..3]
    for (int l = 0; l < 4; ++l) {
        gemm_mfma_kernel<HD><<<ggrid, 256, 0, stream>>>(
            actb, Wlf + (size_t)l * 4 * 2 * 4 * 64 * 8, y, N);
        float* op = (l == 0) ? (out + 64) : (l == 3) ? (out + 128) : nullptr;
        unsigned short* ap = (l == 3) ? nullptr : actb;
        int relu = (l == 3) ? 0 : 1;
        spmm_kernel<<<sgx, 256, 0, stream>>>(y, rowptr, edges, ap, op, N, E2, relu);
    }
}

// Round 12
// 420.062 us; speedup vs baseline: 1.0737x; 1.0737x over previous
//
#include <hip/hip_runtime.h>
#include <cstddef>

#define NREL 4
#define NSUP 2         // super-relations (pairs of relations sharing a dst type)
#define HD 64
#define FD 128
#define BSHIFT 8
#define BUCKET 256     // nodes per bucket
#define CHUNK 16384    // edges per partition block

static inline int idiv_up(int a, int b) { return (a + b - 1) / b; }

typedef __attribute__((ext_vector_type(8))) short bf16x8;
typedef __attribute__((ext_vector_type(4))) float f32x4;

__device__ __forceinline__ unsigned short f2bf(float f) {
    unsigned int u = __float_as_uint(f);
    unsigned int r = (u + 0x7FFFu + ((u >> 16) & 1u)) >> 16;   // RNE
    return (unsigned short)r;
}
__device__ __forceinline__ float bflo(unsigned int v) {
    return __uint_as_float(v << 16);
}
__device__ __forceinline__ float bfhi(unsigned int v) {
    return __uint_as_float(v & 0xFFFF0000u);
}
__device__ __forceinline__ unsigned int cvtpk_bf16(float lo, float hi) {
    unsigned int r;
    asm("v_cvt_pk_bf16_f32 %0, %1, %2" : "=v"(r) : "v"(lo), "v"(hi));
    return r;
}

// ---------------- P1: per-chunk bucket histograms (no global atomics) ----------------
// ccnt[k][c][b] = #edges of chunk c landing in bucket b.

__global__ void pcount_kernel(const int* __restrict__ dst, int* __restrict__ ccnt,
                              int E2, int NBP, int NCH) {
    int k = blockIdx.y;
    int c = blockIdx.x;
    extern __shared__ int lh[];
    for (int i = threadIdx.x; i < NBP; i += blockDim.x) lh[i] = 0;
    __syncthreads();
    const int* dk = dst + (size_t)k * E2;
    int base = c * CHUNK;
    int n = min(CHUNK, E2 - base);
    for (int i = threadIdx.x; i < n; i += blockDim.x)
        atomicAdd(&lh[dk[base + i] >> BSHIFT], 1);
    __syncthreads();
    int* out = ccnt + ((size_t)k * NCH + c) * NBP;
    for (int i = threadIdx.x; i < NBP; i += blockDim.x) out[i] = lh[i];
}

// ---------------- P2: per-bucket chunk-prefix (in place) + cross-bucket scan ----------
// After this: ccnt[k][c][b] = #edges in chunks <c for bucket b; bptr[k][b] = bucket start.

__global__ void pscan_kernel(int* __restrict__ ccnt, int* __restrict__ bptr,
                             int NBP, int NCH, int E2) {
    int k = blockIdx.x;
    int tid = threadIdx.x;          // 256 threads, NBP <= 256
    int* cc = ccnt + (size_t)k * NCH * NBP;
    int total = 0;
    if (tid < NBP) {
        for (int c = 0; c < NCH; ++c) {
            int v = cc[c * NBP + tid];   // coalesced across tid
            cc[c * NBP + tid] = total;
            total += v;
        }
    }
    __shared__ int wsum[4];
    int wid = tid >> 6, lane = tid & 63;
    int x = total;
    #pragma unroll
    for (int off = 1; off < 64; off <<= 1) {
        int y = __shfl_up(x, off, 64);
        if (lane >= off) x += y;
    }
    if (lane == 63) wsum[wid] = x;
    __syncthreads();
    if (tid == 0) {
        int s = 0;
        #pragma unroll
        for (int j = 0; j < 4; ++j) { int t = wsum[j]; wsum[j] = s; s += t; }
    }
    __syncthreads();
    int excl = x - total + wsum[wid];
    if (tid < NBP) bptr[(size_t)k * (NBP + 1) + tid] = excl;
    if (tid == 0) bptr[(size_t)k * (NBP + 1) + NBP] = E2;
}

// ---------------- P3: placement into bucket-grouped staged (LDS atomics only) --------
// staged[pos] = { row17 | (dst_local8 << 17), bits(w) }; row = src + N*(2nd relation).

__global__ void pplace_kernel(const int* __restrict__ src, const int* __restrict__ dst,
                              const float* __restrict__ ew, const int* __restrict__ ccnt,
                              const int* __restrict__ bptr, int2* __restrict__ staged,
                              int E, int E2, int N, int NBP, int NCH) {
    int k = blockIdx.y;
    int c = blockIdx.x;
    extern __shared__ int sh[];
    int* lcnt = sh;          // NBP
    int* lbase = sh + NBP;   // NBP
    const int* cc = ccnt + ((size_t)k * NCH + c) * NBP;
    for (int i = threadIdx.x; i < NBP; i += blockDim.x) {
        lbase[i] = bptr[(size_t)k * (NBP + 1) + i] + cc[i];
        lcnt[i] = 0;
    }
    __syncthreads();
    const int* sk = src + (size_t)k * E2;
    const int* dk = dst + (size_t)k * E2;
    const float* wk = ew + (size_t)k * E2;
    int base = c * CHUNK;
    int n = min(CHUNK, E2 - base);
    int2* out = staged + (size_t)k * E2;
    for (int i = threadIdx.x; i < n; i += blockDim.x) {
        int gi = base + i;
        int d = dk[gi];
        int b = d >> BSHIFT;
        int row = sk[gi] + ((gi >= E) ? N : 0);
        int local = atomicAdd(&lcnt[b], 1);
        out[lbase[b] + local] =
            make_int2(row | ((d & (BUCKET - 1)) << 17), __float_as_int(wk[gi]));
    }
}

// ---------------- pass D: per-bucket LDS counting sort (1024 threads) ----------------
// -> node-sorted 4B edge recs + rowptr

__global__ void bsort_kernel(const int2* __restrict__ staged, const int* __restrict__ bptr,
                             int* __restrict__ rowptr, unsigned int* __restrict__ edges,
                             int E2, int N, int NBP) {
    int k = blockIdx.y;
    int b = blockIdx.x;
    __shared__ int hist[BUCKET];
    __shared__ int excl[BUCKET];
    __shared__ int cur[BUCKET];
    __shared__ int wsum2[4];
    int tid = threadIdx.x;
    int wid = tid >> 6, lane = tid & 63;
    if (tid < BUCKET) hist[tid] = 0;
    __syncthreads();
    int beg = bptr[(size_t)k * (NBP + 1) + b];
    int end = bptr[(size_t)k * (NBP + 1) + b + 1];
    const int2* in = staged + (size_t)k * E2;
    for (int i = beg + tid; i < end; i += blockDim.x)
        atomicAdd(&hist[(in[i].x >> 17) & (BUCKET - 1)], 1);
    __syncthreads();
    int v = 0, x = 0;
    if (tid < BUCKET) {   // 4 full waves scan 64 each
        v = hist[tid];
        x = v;
        #pragma unroll
        for (int off = 1; off < 64; off <<= 1) {
            int y = __shfl_up(x, off, 64);
            if (lane >= off) x += y;
        }
        if (lane == 63) wsum2[wid] = x;
    }
    __syncthreads();
    if (tid == 0) {
        int s = 0;
        #pragma unroll
        for (int j = 0; j < 4; ++j) { int t = wsum2[j]; wsum2[j] = s; s += t; }
    }
    __syncthreads();
    if (tid < BUCKET) {
        int e = x - v + wsum2[wid];
        excl[tid] = e;
        cur[tid] = e;
    }
    __syncthreads();
    unsigned int* outp = edges + (size_t)k * E2;
    for (int i = beg + tid; i < end; i += blockDim.x) {
        int2 q = in[i];
        int dl = (q.x >> 17) & (BUCKET - 1);
        int pos = atomicAdd(&cur[dl], 1);
        unsigned int wb = (unsigned int)(f2bf(__int_as_float(q.y)) & 0x7FFF);
        outp[beg + pos] = ((unsigned int)q.x & 0x1FFFFu) | (wb << 17);
    }
    int node0 = b * BUCKET;
    if (tid < BUCKET && node0 + tid < N)
        rowptr[(size_t)k * (N + 1) + node0 + tid] = beg + excl[tid];
    if (b == 0 && tid == 0) rowptr[(size_t)k * (N + 1) + N] = E2;
}

// ---------------- convert: W -> bf16 fragment-swizzled ----------------
// Wf[mat][kk][n][lane][i] = W[mat][kk*32 + (lane>>4)*8 + i][n*16 + (lane&15)]

__global__ void convw_kernel(const float* __restrict__ W, unsigned short* __restrict__ Wf,
                             int mats, int KK) {
    int tid = blockIdx.x * blockDim.x + threadIdx.x;
    int total = mats * KK * 4 * 64;
    if (tid >= total) return;
    int l = tid & 63;
    int n = (tid >> 6) & 3;
    int rest = tid >> 8;
    int kk = rest % KK;
    int mat = rest / KK;
    int h = l >> 4, c = l & 15;
    int K = KK * 32;
    const float* Wm = W + (size_t)mat * K * 64;
    unsigned short* o = Wf + (size_t)tid * 8;
    #pragma unroll
    for (int i = 0; i < 8; ++i)
        o[i] = f2bf(Wm[(size_t)(kk * 32 + h * 8 + i) * 64 + n * 16 + c]);
}

// ---------------- MFMA GEMM (bf16 X input): Y[rel] = X_{rel%2} @ W_rel ----------

template <int K>
__global__ void gemm_mfma_kernel(const unsigned short* __restrict__ Xb,
                                 const unsigned short* __restrict__ Wf,
                                 unsigned short* __restrict__ Ybase, int N) {
    constexpr int KK = K / 32;
    int rel = blockIdx.y;
    const unsigned short* X = Xb + (size_t)(rel & 1) * N * K;
    const bf16x8* Wv = reinterpret_cast<const bf16x8*>(Wf + (size_t)rel * KK * 4 * 64 * 8);
    unsigned short* Y = Ybase + (size_t)rel * N * HD;
    int tid = threadIdx.x;
    int w = tid >> 6, l = tid & 63;
    int lr = l & 15, lh = l >> 4;
    int row0 = blockIdx.x * 128 + w * 32;
    f32x4 acc00 = {0.f,0.f,0.f,0.f}, acc01 = {0.f,0.f,0.f,0.f};
    f32x4 acc02 = {0.f,0.f,0.f,0.f}, acc03 = {0.f,0.f,0.f,0.f};
    f32x4 acc10 = {0.f,0.f,0.f,0.f}, acc11 = {0.f,0.f,0.f,0.f};
    f32x4 acc12 = {0.f,0.f,0.f,0.f}, acc13 = {0.f,0.f,0.f,0.f};
    int r0 = min(row0 + lr, N - 1);
    int r1 = min(row0 + 16 + lr, N - 1);
    const unsigned short* xp0 = X + (size_t)r0 * K + lh * 8;
    const unsigned short* xp1 = X + (size_t)r1 * K + lh * 8;
    #pragma unroll
    for (int kk = 0; kk < KK; ++kk) {
        bf16x8 a0 = *reinterpret_cast<const bf16x8*>(xp0 + kk * 32);
        bf16x8 a1 = *reinterpret_cast<const bf16x8*>(xp1 + kk * 32);
        bf16x8 b0 = Wv[(kk * 4 + 0) * 64 + l];
        bf16x8 b1 = Wv[(kk * 4 + 1) * 64 + l];
        bf16x8 b2 = Wv[(kk * 4 + 2) * 64 + l];
        bf16x8 b3 = Wv[(kk * 4 + 3) * 64 + l];
        acc00 = __builtin_amdgcn_mfma_f32_16x16x32_bf16(a0, b0, acc00, 0, 0, 0);
        acc01 = __builtin_amdgcn_mfma_f32_16x16x32_bf16(a0, b1, acc01, 0, 0, 0);
        acc02 = __builtin_amdgcn_mfma_f32_16x16x32_bf16(a0, b2, acc02, 0, 0, 0);
        acc03 = __builtin_amdgcn_mfma_f32_16x16x32_bf16(a0, b3, acc03, 0, 0, 0);
        acc10 = __builtin_amdgcn_mfma_f32_16x16x32_bf16(a1, b0, acc10, 0, 0, 0);
        acc11 = __builtin_amdgcn_mfma_f32_16x16x32_bf16(a1, b1, acc11, 0, 0, 0);
        acc12 = __builtin_amdgcn_mfma_f32_16x16x32_bf16(a1, b2, acc12, 0, 0, 0);
        acc13 = __builtin_amdgcn_mfma_f32_16x16x32_bf16(a1, b3, acc13, 0, 0, 0);
    }
    // C/D layout: col = lane&15, row(in tile) = (lane>>4)*4 + reg  [HW-verified]
    #pragma unroll
    for (int reg = 0; reg < 4; ++reg) {
        int rowa = row0 + lh * 4 + reg;
        if (rowa < N) {
            unsigned short* yp = Y + (size_t)rowa * HD + lr;
            yp[0]  = f2bf(acc00[reg]);
            yp[16] = f2bf(acc01[reg]);
            yp[32] = f2bf(acc02[reg]);
            yp[48] = f2bf(acc03[reg]);
        }
        int rowb = row0 + 16 + lh * 4 + reg;
        if (rowb < N) {
            unsigned short* yp = Y + (size_t)rowb * HD + lr;
            yp[0]  = f2bf(acc10[reg]);
            yp[16] = f2bf(acc11[reg]);
            yp[32] = f2bf(acc12[reg]);
            yp[48] = f2bf(acc13[reg]);
        }
    }
}

// ---------------- MFMA GEMM (f32 X input, in-register v_cvt_pk_bf16_f32): layer 1 ----

__global__ void gemm_mfma_f32in_kernel(const float* __restrict__ X0,
                                       const float* __restrict__ X1,
                                       const unsigned short* __restrict__ Wf,
                                       unsigned short* __restrict__ Ybase, int N) {
    constexpr int K = FD;
    constexpr int KK = K / 32;
    int rel = blockIdx.y;
    const float* X = (rel & 1) ? X1 : X0;
    const bf16x8* Wv = reinterpret_cast<const bf16x8*>(Wf + (size_t)rel * KK * 4 * 64 * 8);
    unsigned short* Y = Ybase + (size_t)rel * N * HD;
    int tid = threadIdx.x;
    int w = tid >> 6, l = tid & 63;
    int lr = l & 15, lh = l >> 4;
    int row0 = blockIdx.x * 128 + w * 32;
    f32x4 acc00 = {0.f,0.f,0.f,0.f}, acc01 = {0.f,0.f,0.f,0.f};
    f32x4 acc02 = {0.f,0.f,0.f,0.f}, acc03 = {0.f,0.f,0.f,0.f};
    f32x4 acc10 = {0.f,0.f,0.f,0.f}, acc11 = {0.f,0.f,0.f,0.f};
    f32x4 acc12 = {0.f,0.f,0.f,0.f}, acc13 = {0.f,0.f,0.f,0.f};
    int r0 = min(row0 + lr, N - 1);
    int r1 = min(row0 + 16 + lr, N - 1);
    const float* xp0 = X + (size_t)r0 * K + lh * 8;
    const float* xp1 = X + (size_t)r1 * K + lh * 8;
    #pragma unroll
    for (int kk = 0; kk < KK; ++kk) {
        float4 xa0 = *reinterpret_cast<const float4*>(xp0 + kk * 32);
        float4 xa1 = *reinterpret_cast<const float4*>(xp0 + kk * 32 + 4);
        float4 xb0 = *reinterpret_cast<const float4*>(xp1 + kk * 32);
        float4 xb1 = *reinterpret_cast<const float4*>(xp1 + kk * 32 + 4);
        union { unsigned int u[4]; bf16x8 v; } ca, cb;
        ca.u[0] = cvtpk_bf16(xa0.x, xa0.y);
        ca.u[1] = cvtpk_bf16(xa0.z, xa0.w);
        ca.u[2] = cvtpk_bf16(xa1.x, xa1.y);
        ca.u[3] = cvtpk_bf16(xa1.z, xa1.w);
        cb.u[0] = cvtpk_bf16(xb0.x, xb0.y);
        cb.u[1] = cvtpk_bf16(xb0.z, xb0.w);
        cb.u[2] = cvtpk_bf16(xb1.x, xb1.y);
        cb.u[3] = cvtpk_bf16(xb1.z, xb1.w);
        bf16x8 a0 = ca.v;
        bf16x8 a1 = cb.v;
        bf16x8 b0 = Wv[(kk * 4 + 0) * 64 + l];
        bf16x8 b1 = Wv[(kk * 4 + 1) * 64 + l];
        bf16x8 b2 = Wv[(kk * 4 + 2) * 64 + l];
        bf16x8 b3 = Wv[(kk * 4 + 3) * 64 + l];
        acc00 = __builtin_amdgcn_mfma_f32_16x16x32_bf16(a0, b0, acc00, 0, 0, 0);
        acc01 = __builtin_amdgcn_mfma_f32_16x16x32_bf16(a0, b1, acc01, 0, 0, 0);
        acc02 = __builtin_amdgcn_mfma_f32_16x16x32_bf16(a0, b2, acc02, 0, 0, 0);
        acc03 = __builtin_amdgcn_mfma_f32_16x16x32_bf16(a0, b3, acc03, 0, 0, 0);
        acc10 = __builtin_amdgcn_mfma_f32_16x16x32_bf16(a1, b0, acc10, 0, 0, 0);
        acc11 = __builtin_amdgcn_mfma_f32_16x16x32_bf16(a1, b1, acc11, 0, 0, 0);
        acc12 = __builtin_amdgcn_mfma_f32_16x16x32_bf16(a1, b2, acc12, 0, 0, 0);
        acc13 = __builtin_amdgcn_mfma_f32_16x16x32_bf16(a1, b3, acc13, 0, 0, 0);
    }
    #pragma unroll
    for (int reg = 0; reg < 4; ++reg) {
        int rowa = row0 + lh * 4 + reg;
        if (rowa < N) {
            unsigned short* yp = Y + (size_t)rowa * HD + lr;
            yp[0]  = f2bf(acc00[reg]);
            yp[16] = f2bf(acc01[reg]);
            yp[32] = f2bf(acc02[reg]);
            yp[48] = f2bf(acc03[reg]);
        }
        int rowb = row0 + 16 + lh * 4 + reg;
        if (rowb < N) {
            unsigned short* yp = Y + (size_t)rowb * HD + lr;
            yp[0]  = f2bf(acc10[reg]);
            yp[16] = f2bf(acc11[reg]);
            yp[32] = f2bf(acc12[reg]);
            yp[48] = f2bf(acc13[reg]);
        }
    }
}

// ---------------- SpMM gather: one wave per dst node, combined relation pair ----------
// edge rec: row17 | wbf15<<17 (row < 2N indexes the contiguous y pair for this type).
// h = lane>>4 edge slot (4 edges per gather instr), c4 = (lane&15)*4 column quad
// (uint2 = 4 bf16 = 8 B/lane; 16 lanes cover a 128 B row). 16-edge predicated
// batches; 4 paired gathers (16 edges) in flight. XCD pinning: id%8 -> group.

__global__ void spmm_kernel(const unsigned short* __restrict__ Ybase,
                            const int* __restrict__ rowptr, const unsigned int* __restrict__ edges,
                            unsigned short* __restrict__ act, float* __restrict__ outp,
                            int N, int E2, int relu) {
    int id = blockIdx.x;
    int g = id & 7;
    int t = g >> 2;
    int pbi = (id >> 3) * 4 + (g & 3);
    int wave = threadIdx.x >> 6;
    int lane = threadIdx.x & 63;
    int d = pbi * 4 + wave;
    if (d >= N) return;
    int h = lane >> 4;          // edge slot 0..3
    int c4 = (lane & 15) * 4;   // column quad
    const unsigned short* Y = Ybase + (size_t)(2 * t) * N * HD;
    const unsigned int* ep = edges + (size_t)t * E2;
    int beg = rowptr[(size_t)t * (N + 1) + d];
    int end = rowptr[(size_t)t * (N + 1) + d + 1];
    float4 a0 = {0.f,0.f,0.f,0.f}, a1 = {0.f,0.f,0.f,0.f};
    float4 a2 = {0.f,0.f,0.f,0.f}, a3 = {0.f,0.f,0.f,0.f};
    if (beg < end) {
        int endm1 = end - 1;
        unsigned int m0, m1, m2, m3;
        {
            int i0 = beg + 0 + h, i1 = beg + 4 + h, i2 = beg + 8 + h, i3 = beg + 12 + h;
            m0 = ep[i0 < end ? i0 : endm1];
            m1 = ep[i1 < end ? i1 : endm1];
            m2 = ep[i2 < end ? i2 : endm1];
            m3 = ep[i3 < end ? i3 : endm1];
        }
        for (int base = beg; ; ) {
            int nb = base + 16;
            bool more = nb < end;
            unsigned int n0, n1, n2, n3;
            if (more) {
                int i0 = nb + 0 + h, i1 = nb + 4 + h, i2 = nb + 8 + h, i3 = nb + 12 + h;
                n0 = ep[i0 < end ? i0 : endm1];
                n1 = ep[i1 < end ? i1 : endm1];
                n2 = ep[i2 < end ? i2 : endm1];
                n3 = ep[i3 < end ? i3 : endm1];
            }
            uint2 y0 = *reinterpret_cast<const uint2*>(Y + ((m0 & 0x1FFFFu) * HD + c4));
            uint2 y1 = *reinterpret_cast<const uint2*>(Y + ((m1 & 0x1FFFFu) * HD + c4));
            uint2 y2 = *reinterpret_cast<const uint2*>(Y + ((m2 & 0x1FFFFu) * HD + c4));
            uint2 y3 = *reinterpret_cast<const uint2*>(Y + ((m3 & 0x1FFFFu) * HD + c4));
            float w0 = ((base + 0 + h) < end) ? __uint_as_float((m0 >> 17) << 16) : 0.f;
            float w1 = ((base + 4 + h) < end) ? __uint_as_float((m1 >> 17) << 16) : 0.f;
            float w2 = ((base + 8 + h) < end) ? __uint_as_float((m2 >> 17) << 16) : 0.f;
            float w3 = ((base + 12 + h) < end) ? __uint_as_float((m3 >> 17) << 16) : 0.f;
            a0.x += w0 * bflo(y0.x); a0.y += w0 * bfhi(y0.x);
            a0.z += w0 * bflo(y0.y); a0.w += w0 * bfhi(y0.y);
            a1.x += w1 * bflo(y1.x); a1.y += w1 * bfhi(y1.x);
            a1.z += w1 * bflo(y1.y); a1.w += w1 * bfhi(y1.y);
            a2.x += w2 * bflo(y2.x); a2.y += w2 * bfhi(y2.x);
            a2.z += w2 * bflo(y2.y); a2.w += w2 * bfhi(y2.y);
            a3.x += w3 * bflo(y3.x); a3.y += w3 * bfhi(y3.x);
            a3.z += w3 * bflo(y3.y); a3.w += w3 * bfhi(y3.y);
            if (!more) break;
            base = nb;
            m0 = n0; m1 = n1; m2 = n2; m3 = n3;
        }
    }
    float4 s;
    s.x = (a0.x + a1.x) + (a2.x + a3.x);
    s.y = (a0.y + a1.y) + (a2.y + a3.y);
    s.z = (a0.z + a1.z) + (a2.z + a3.z);
    s.w = (a0.w + a1.w) + (a2.w + a3.w);
    s.x += __shfl_xor(s.x, 16, 64);  s.x += __shfl_xor(s.x, 32, 64);
    s.y += __shfl_xor(s.y, 16, 64);  s.y += __shfl_xor(s.y, 32, 64);
    s.z += __shfl_xor(s.z, 16, 64);  s.z += __shfl_xor(s.z, 32, 64);
    s.w += __shfl_xor(s.w, 16, 64);  s.w += __shfl_xor(s.w, 32, 64);
    if (relu) {
        s.x = fmaxf(s.x, 0.f); s.y = fmaxf(s.y, 0.f);
        s.z = fmaxf(s.z, 0.f); s.w = fmaxf(s.w, 0.f);
    }
    if (lane < 16) {
        if (act) {
            ushort4 ob;
            ob.x = f2bf(s.x); ob.y = f2bf(s.y); ob.z = f2bf(s.z); ob.w = f2bf(s.w);
            *reinterpret_cast<ushort4*>(&act[((size_t)t * N + d) * HD + c4]) = ob;
        }
        if (outp) *reinterpret_cast<float4*>(&outp[((size_t)t * N + d) * 192 + c4]) = s;
    }
}

// ---------------- orchestration ----------------

extern "C" void kernel_launch(void* const* d_in, const int* in_sizes, int n_in,
                              void* d_out, int out_size, void* d_ws, size_t ws_size,
                              hipStream_t stream) {
    const float* x0 = (const float*)d_in[0];
    const float* x1 = (const float*)d_in[1];
    const int* src = (const int*)d_in[2];
    const int* dst = (const int*)d_in[3];
    const float* ew = (const float*)d_in[4];
    const float* W1 = (const float*)d_in[5];
    const float* Wl = (const float*)d_in[6];
    float* out = (float*)d_out;

    int N = in_sizes[0] / FD;
    int E = in_sizes[2] / NREL;
    int E2 = 2 * E;                 // edges per super-relation
    int NBP = idiv_up(N, BUCKET);   // 196 for N=50000 (must be <= 256 for pscan)
    int NCH = idiv_up(E2, CHUNK);   // 98

    char* ws = (char*)d_ws;
    size_t off = 0;
    auto alloc = [&](size_t bytes) -> void* {
        void* p = ws + off;
        off = (off + bytes + 255) & ~(size_t)255;
        return p;
    };
    int* ccnt    = (int*)alloc((size_t)NSUP * NCH * NBP * 4);
    int* bptr    = (int*)alloc((size_t)NSUP * (NBP + 1) * 4);
    int* rowptr  = (int*)alloc((size_t)NSUP * (N + 1) * 4);
    unsigned int* edges = (unsigned int*)alloc((size_t)NSUP * E2 * 4);
    unsigned short* y    = (unsigned short*)alloc((size_t)NREL * N * HD * 2);
    unsigned short* actb = (unsigned short*)alloc((size_t)2 * N * HD * 2);
    unsigned short* W1f  = (unsigned short*)alloc((size_t)NREL * 4 * 4 * 64 * 8 * 2);
    unsigned short* Wlf  = (unsigned short*)alloc((size_t)16 * 2 * 4 * 64 * 8 * 2);
    int2* staged = (int2*)alloc((size_t)NSUP * E2 * 8);   // dead after bsort
    (void)ws_size;

    // weight converts (x0/x1 convert fused into layer-1 GEMM)
    convw_kernel<<<idiv_up(NREL * 4 * 4 * 64, 256), 256, 0, stream>>>(W1, W1f, NREL, 4);
    convw_kernel<<<idiv_up(16 * 2 * 4 * 64, 256), 256, 0, stream>>>(Wl, Wlf, 16, 2);

    // deterministic 3-phase bucket partition + per-bucket counting sort (no global atomics)
    pcount_kernel<<<dim3(NCH, NSUP), 1024, NBP * 4, stream>>>(dst, ccnt, E2, NBP, NCH);
    pscan_kernel<<<NSUP, 256, 0, stream>>>(ccnt, bptr, NBP, NCH, E2);
    pplace_kernel<<<dim3(NCH, NSUP), 1024, 2 * NBP * 4, stream>>>(
        src, dst, ew, ccnt, bptr, staged, E, E2, N, NBP, NCH);
    bsort_kernel<<<dim3(NBP, NSUP), 1024, 0, stream>>>(staged, bptr, rowptr, edges, E2, N, NBP);

    dim3 ggrid(idiv_up(N, 128), NREL);
    int NB4 = idiv_up(N, 4);
    int sgx = idiv_up(NB4, 4) * 8;   // flat grid, id%8 -> (type, xcd-slot)

    // layer 1: h1 = relu(spmm(x @ W1)); store act(bf16) + out[:, :, 0:64]
    gemm_mfma_f32in_kernel<<<ggrid, 256, 0, stream>>>(x0, x1, W1f, y, N);
    spmm_kernel<<<sgx, 256, 0, stream>>>(y, rowptr, edges, actb, out + 0, N, E2, 1);

    // layers 2..5 with Wl[0..3]
    for (int l = 0; l < 4; ++l) {
        gemm_mfma_kernel<HD><<<ggrid, 256, 0, stream>>>(
            actb, Wlf + (size_t)l * 4 * 2 * 4 * 64 * 8, y, N);
        float* op = (l == 0) ? (out + 64) : (l == 3) ? (out + 128) : nullptr;
        unsigned short* ap = (l == 3) ? nullptr : actb;
        int relu = (l == 3) ? 0 : 1;
        spmm_kernel<<<sgx, 256, 0, stream>>>(y, rowptr, edges, ap, op, N, E2, relu);
    }
}